// Round 3
// baseline (5590.277 us; speedup 1.0000x reference)
//
#include <hip/hip_runtime.h>

#define B_ 64
#define T_ 2048
#define F_ 8
#define H_ 128
#define G_ 512   // 4*H

typedef _Float16 v2h __attribute__((ext_vector_type(2)));

// pack two fp32 into one dword of two f16 (RTN)
__device__ __forceinline__ unsigned pk2h(float lo, float hi) {
    v2h p;
    p[0] = (_Float16)lo;
    p[1] = (_Float16)hi;
    return __builtin_bit_cast(unsigned, p);
}

#if __has_builtin(__builtin_amdgcn_fdot2)
__device__ __forceinline__ float fdot2a(unsigned a, unsigned b, float c) {
    return __builtin_amdgcn_fdot2(__builtin_bit_cast(v2h, a),
                                  __builtin_bit_cast(v2h, b), c, false);
}
#else
__device__ __forceinline__ float fdot2a(unsigned a, unsigned b, float c) {
    v2h av = __builtin_bit_cast(v2h, a);
    v2h bv = __builtin_bit_cast(v2h, b);
    c += (float)av[0] * (float)bv[0];
    c += (float)av[1] * (float)bv[1];
    return c;
}
#endif

__device__ __forceinline__ float tanh_f(float x) {
    float e = __expf(2.0f * x);
    return 1.0f - 2.0f / (e + 1.0f);
}

__global__ __launch_bounds__(1024, 4)
void lstm2_fused_kernel(const float* __restrict__ x,
                        const float* __restrict__ wih0,
                        const float* __restrict__ whh0,
                        const float* __restrict__ bih0,
                        const float* __restrict__ bhh0,
                        const float* __restrict__ wih1,
                        const float* __restrict__ whh1,
                        const float* __restrict__ bih1,
                        const float* __restrict__ bhh1,
                        const float* __restrict__ wlin,
                        const float* __restrict__ blin,
                        float* __restrict__ out)
{
    __shared__ __align__(16) unsigned x_lds[T_ * F_ / 2];  // 8192 dwords = 32 KB f16 pairs
    __shared__ __align__(16) unsigned h0b[2][H_ / 2];      // h0 double-buffered, f16 pairs
    __shared__ __align__(16) unsigned h1b[2][H_ / 2];      // h1 double-buffered
    __shared__ __align__(16) unsigned wlin_p[G_];          // w_lin packed f16 pairs
    __shared__ float blin_f[F_];

    const int tid = threadIdx.x;        // 0..1023
    const int j   = tid >> 3;           // h index 0..127
    const int q   = (tid >> 1) & 3;     // gate: 0=i 1=f 2=g(tanh) 3=o
    const int s   = tid & 1;            // K-half
    const int g   = q * H_ + j;         // gate row (PyTorch i,f,g,o)
    const int b   = blockIdx.x;

    // ---- stage x[b] (fp32) into LDS as packed f16 pairs ----
    const float4* xp = (const float4*)(x + (size_t)b * T_ * F_);
    #pragma unroll
    for (int i = 0; i < 4; ++i) {
        int idx = tid + i * 1024;       // float4 index, 4096 total
        float4 v = xp[idx];
        x_lds[idx * 2 + 0] = pk2h(v.x, v.y);
        x_lds[idx * 2 + 1] = pk2h(v.z, v.w);
    }

    // ---- per-thread weight half-rows -> VGPRs (packed f16 pairs) ----
    unsigned rwih0[2];
    {
        float4 v = *(const float4*)(wih0 + (size_t)g * F_ + s * 4);
        rwih0[0] = pk2h(v.x, v.y);
        rwih0[1] = pk2h(v.z, v.w);
    }
    unsigned rwhh0[32], rwih1[32], rwhh1[32];
    {
        const float4* p = (const float4*)(whh0 + (size_t)g * H_ + s * 64);
        #pragma unroll
        for (int i = 0; i < 16; ++i) {
            float4 v = p[i];
            rwhh0[i * 2 + 0] = pk2h(v.x, v.y);
            rwhh0[i * 2 + 1] = pk2h(v.z, v.w);
        }
    }
    {
        const float4* p = (const float4*)(wih1 + (size_t)g * H_ + s * 64);
        #pragma unroll
        for (int i = 0; i < 16; ++i) {
            float4 v = p[i];
            rwih1[i * 2 + 0] = pk2h(v.x, v.y);
            rwih1[i * 2 + 1] = pk2h(v.z, v.w);
        }
    }
    {
        const float4* p = (const float4*)(whh1 + (size_t)g * H_ + s * 64);
        #pragma unroll
        for (int i = 0; i < 16; ++i) {
            float4 v = p[i];
            rwhh1[i * 2 + 0] = pk2h(v.x, v.y);
            rwhh1[i * 2 + 1] = pk2h(v.z, v.w);
        }
    }
    const float bias0 = s ? 0.0f : (bih0[g] + bhh0[g]);
    const float bias1 = s ? 0.0f : (bih1[g] + bhh1[g]);

    // w_lin [8][128] -> 512 packed pairs; pair p = fo*64 + k covers h = 2k,2k+1
    if (tid < G_) {
        wlin_p[tid] = pk2h(wlin[tid * 2], wlin[tid * 2 + 1]);
    }
    if (tid < F_) blin_f[tid] = blin[tid];
    if (tid < H_) { ((unsigned*)h0b)[tid] = 0u; ((unsigned*)h1b)[tid] = 0u; }
    __syncthreads();

    // branchless activation: act = 1 - A2 / (exp(KK*pre) + 1)
    // sigmoid: A2=1, KK=1;  tanh (q==2): A2=2, KK=2
    const float A2 = (q == 2) ? 2.0f : 1.0f;
    const float KK = A2;

    float c0 = 0.0f, c1 = 0.0f;   // owned by lanes with (tid&7)==0
    int p = 0;

    for (int t = 0; t < T_; ++t) {
        // ---------- layer 0 gates ----------
        float acc0 = bias0, acc1 = 0.0f;
        {
            uint2 xv = *(const uint2*)&x_lds[t * 4 + s * 2];
            acc0 = fdot2a(rwih0[0], xv.x, acc0);
            acc1 = fdot2a(rwih0[1], xv.y, acc1);
        }
        #pragma unroll
        for (int k = 0; k < 8; ++k) {
            uint4 hv = *(const uint4*)&h0b[p][s * 32 + k * 4];
            acc0 = fdot2a(rwhh0[k * 4 + 0], hv.x, acc0);
            acc1 = fdot2a(rwhh0[k * 4 + 1], hv.y, acc1);
            acc0 = fdot2a(rwhh0[k * 4 + 2], hv.z, acc0);
            acc1 = fdot2a(rwhh0[k * 4 + 3], hv.w, acc1);
        }
        float pre = acc0 + acc1;
        pre += __shfl_xor(pre, 1);
        float act = 1.0f - A2 / (__expf(KK * pre) + 1.0f);
        // gather 4 gates of h-index j (lanes base,base+2,base+4,base+6)
        float gf = __shfl_down(act, 2);
        float gg = __shfl_down(act, 4);
        float go = __shfl_down(act, 6);
        if ((tid & 7) == 0) {
            c0 = gf * c0 + act * gg;
            float hh = go * tanh_f(c0);
            ((_Float16*)h0b[1 - p])[j] = (_Float16)hh;
        }
        __syncthreads();

        // ---------- layer 1 gates (input = new h0, recurrent = old h1) ----------
        acc0 = bias1; acc1 = 0.0f;
        #pragma unroll
        for (int k = 0; k < 8; ++k) {
            uint4 hv = *(const uint4*)&h0b[1 - p][s * 32 + k * 4];
            acc0 = fdot2a(rwih1[k * 4 + 0], hv.x, acc0);
            acc1 = fdot2a(rwih1[k * 4 + 1], hv.y, acc1);
            acc0 = fdot2a(rwih1[k * 4 + 2], hv.z, acc0);
            acc1 = fdot2a(rwih1[k * 4 + 3], hv.w, acc1);
        }
        #pragma unroll
        for (int k = 0; k < 8; ++k) {
            uint4 hv = *(const uint4*)&h1b[p][s * 32 + k * 4];
            acc0 = fdot2a(rwhh1[k * 4 + 0], hv.x, acc0);
            acc1 = fdot2a(rwhh1[k * 4 + 1], hv.y, acc1);
            acc0 = fdot2a(rwhh1[k * 4 + 2], hv.z, acc0);
            acc1 = fdot2a(rwhh1[k * 4 + 3], hv.w, acc1);
        }
        pre = acc0 + acc1;
        pre += __shfl_xor(pre, 1);
        act = 1.0f - A2 / (__expf(KK * pre) + 1.0f);
        gf = __shfl_down(act, 2);
        gg = __shfl_down(act, 4);
        go = __shfl_down(act, 6);
        if ((tid & 7) == 0) {
            c1 = gf * c1 + act * gg;
            float hh = go * tanh_f(c1);
            ((_Float16*)h1b[1 - p])[j] = (_Float16)hh;
        }
        __syncthreads();

        // ---------- output linear: wave 0, overlaps next step's dots ----------
        if (tid < 64) {
            int fo = tid >> 3;      // output feature 0..7
            int l  = tid & 7;       // 8 lanes per feature
            float a = 0.0f;
            #pragma unroll
            for (int jj = 0; jj < 8; ++jj) {
                a = fdot2a(wlin_p[fo * 64 + l * 8 + jj], h1b[1 - p][l * 8 + jj], a);
            }
            a += __shfl_down(a, 4, 8);
            a += __shfl_down(a, 2, 8);
            a += __shfl_down(a, 1, 8);
            if (l == 0) {
                out[((size_t)b * T_ + t) * F_ + fo] = a + blin_f[fo];
            }
        }
        p ^= 1;
    }
}

extern "C" void kernel_launch(void* const* d_in, const int* in_sizes, int n_in,
                              void* d_out, int out_size, void* d_ws, size_t ws_size,
                              hipStream_t stream) {
    const float* x    = (const float*)d_in[0];
    const float* wih0 = (const float*)d_in[1];
    const float* whh0 = (const float*)d_in[2];
    const float* bih0 = (const float*)d_in[3];
    const float* bhh0 = (const float*)d_in[4];
    const float* wih1 = (const float*)d_in[5];
    const float* whh1 = (const float*)d_in[6];
    const float* bih1 = (const float*)d_in[7];
    const float* bhh1 = (const float*)d_in[8];
    const float* wlin = (const float*)d_in[9];
    const float* blin = (const float*)d_in[10];
    float* out = (float*)d_out;

    lstm2_fused_kernel<<<dim3(B_), dim3(1024), 0, stream>>>(
        x, wih0, whh0, bih0, bhh0, wih1, whh1, bih1, bhh1, wlin, blin, out);
}

// Round 4
// 5513.358 us; speedup vs baseline: 1.0140x; 1.0140x over previous
//
#include <hip/hip_runtime.h>

#define B_ 64
#define T_ 2048
#define F_ 8
#define H_ 128
#define G_ 512   // 4*H

typedef _Float16 v2h __attribute__((ext_vector_type(2)));

// pack two fp32 into one dword of two f16 (RTN)
__device__ __forceinline__ unsigned pk2h(float lo, float hi) {
    v2h p;
    p[0] = (_Float16)lo;
    p[1] = (_Float16)hi;
    return __builtin_bit_cast(unsigned, p);
}

#if __has_builtin(__builtin_amdgcn_fdot2)
__device__ __forceinline__ float fdot2a(unsigned a, unsigned b, float c) {
    return __builtin_amdgcn_fdot2(__builtin_bit_cast(v2h, a),
                                  __builtin_bit_cast(v2h, b), c, false);
}
#else
__device__ __forceinline__ float fdot2a(unsigned a, unsigned b, float c) {
    v2h av = __builtin_bit_cast(v2h, a);
    v2h bv = __builtin_bit_cast(v2h, b);
    c += (float)av[0] * (float)bv[0];
    c += (float)av[1] * (float)bv[1];
    return c;
}
#endif

__device__ __forceinline__ float tanh_f(float x) {
    float e = __expf(2.0f * x);
    return 1.0f - 2.0f / (e + 1.0f);
}

// 8-lane compacting butterfly: input 4 gate-partials, output: lane base+0 holds
// gate0(i), +1 holds gate2(g), +2 holds gate1(f), +3 holds gate3(o) full sums
// (lanes +4..+7 mirror +0..+3).
__device__ __forceinline__ float red8(float v0, float v1, float v2, float v3, int l) {
    float s0 = v0 + __shfl_xor(v0, 1);
    float s1 = v1 + __shfl_xor(v1, 1);
    float s2 = v2 + __shfl_xor(v2, 1);
    float s3 = v3 + __shfl_xor(v3, 1);
    float u0 = (l & 1) ? s2 : s0;
    float u1 = (l & 1) ? s3 : s1;
    float z0 = u0 + __shfl_xor(u0, 2);
    float z1 = u1 + __shfl_xor(u1, 2);
    float w  = (l & 2) ? z1 : z0;
    w += __shfl_xor(w, 4);
    return w;
}

__global__ void __launch_bounds__(1024)
__attribute__((amdgpu_waves_per_eu(4, 4)))
lstm2_fused_kernel(const float* __restrict__ x,
                   const float* __restrict__ wih0,
                   const float* __restrict__ whh0,
                   const float* __restrict__ bih0,
                   const float* __restrict__ bhh0,
                   const float* __restrict__ wih1,
                   const float* __restrict__ whh1,
                   const float* __restrict__ bih1,
                   const float* __restrict__ bhh1,
                   const float* __restrict__ wlin,
                   const float* __restrict__ blin,
                   float* __restrict__ out)
{
    __shared__ __align__(16) unsigned x_lds[T_ * F_ / 2];  // 32 KB packed f16 x
    __shared__ __align__(16) unsigned h0b[2][H_ / 2];      // h0 double-buffered
    __shared__ __align__(16) unsigned h1b[2][H_ / 2];      // h1 double-buffered
    __shared__ __align__(16) unsigned wlin_p[G_];
    __shared__ float blin_f[F_];

    const int tid = threadIdx.x;    // 0..1023
    const int j   = tid >> 3;       // h index 0..127
    const int l   = tid & 7;        // K-slice / lane-in-group
    const int b   = blockIdx.x;
    // gate owned by this lane after red8 compaction: 0->i,1->g,2->f,3->o
    const int l3   = l & 3;
    const int gate = ((l3 & 1) << 1) | (l3 >> 1);   // 0,2,1,3

    // ---- stage x[b] into LDS as packed f16 pairs ----
    const float4* xp = (const float4*)(x + (size_t)b * T_ * F_);
    #pragma unroll
    for (int i = 0; i < 4; ++i) {
        int idx = tid + i * 1024;
        float4 v = xp[idx];
        x_lds[idx * 2 + 0] = pk2h(v.x, v.y);
        x_lds[idx * 2 + 1] = pk2h(v.z, v.w);
    }

    // ---- weights: rows {q*128+j}, K-slice [16l,16l+16), all 3 matrices ----
    unsigned rwhh0[32], rwih1[32], rwhh1[32];   // [q*8 + d]
    float    w0f[4];                            // wih0[q*128+j][l] (f32)
    #pragma unroll
    for (int q = 0; q < 4; ++q) {
        const float4* p0 = (const float4*)(whh0 + (size_t)(q * H_ + j) * H_ + l * 16);
        const float4* p1 = (const float4*)(wih1 + (size_t)(q * H_ + j) * H_ + l * 16);
        const float4* p2 = (const float4*)(whh1 + (size_t)(q * H_ + j) * H_ + l * 16);
        #pragma unroll
        for (int i = 0; i < 4; ++i) {
            float4 v0 = p0[i], v1 = p1[i], v2 = p2[i];
            rwhh0[q * 8 + i * 2 + 0] = pk2h(v0.x, v0.y);
            rwhh0[q * 8 + i * 2 + 1] = pk2h(v0.z, v0.w);
            rwih1[q * 8 + i * 2 + 0] = pk2h(v1.x, v1.y);
            rwih1[q * 8 + i * 2 + 1] = pk2h(v1.z, v1.w);
            rwhh1[q * 8 + i * 2 + 0] = pk2h(v2.x, v2.y);
            rwhh1[q * 8 + i * 2 + 1] = pk2h(v2.z, v2.w);
        }
        w0f[q] = wih0[(size_t)(q * H_ + j) * F_ + l];
    }
    // per-lane bias for the gate this lane ends up owning
    const float bias0 = bih0[gate * H_ + j] + bhh0[gate * H_ + j];
    const float bias1 = bih1[gate * H_ + j] + bhh1[gate * H_ + j];
    const float A2 = (gate == 2) ? 2.0f : 1.0f;   // tanh for g-gate, sigmoid else

    if (tid < G_) wlin_p[tid] = pk2h(wlin[tid * 2], wlin[tid * 2 + 1]);
    if (tid < F_) blin_f[tid] = blin[tid];
    if (tid < H_) { ((unsigned*)h0b)[tid] = 0u; ((unsigned*)h1b)[tid] = 0u; }
    __syncthreads();

    const int bl = (tid & 63) & ~7;   // wave-lane base of this 8-group
    float c0 = 0.0f, c1 = 0.0f;       // replicated across all 8 lanes of group
    int p = 0;

    for (int t = 0; t < T_; ++t) {
        // ================= layer 0 =================
        float a0, a1, a2, a3;
        {   // x contribution: lane l handles feature l
            unsigned d = x_lds[t * 4 + (l >> 1)];
            v2h hp = __builtin_bit_cast(v2h, d);
            float xv = (float)hp[l & 1];
            a0 = w0f[0] * xv; a1 = w0f[1] * xv;
            a2 = w0f[2] * xv; a3 = w0f[3] * xv;
        }
        {
            uint4 hA = *(const uint4*)&h0b[p][l * 8];
            uint4 hB = *(const uint4*)&h0b[p][l * 8 + 4];
            #pragma unroll
            for (int q = 0; q < 4; ++q) {
                float* aq = (q == 0) ? &a0 : (q == 1) ? &a1 : (q == 2) ? &a2 : &a3;
                float a = *aq;
                a = fdot2a(rwhh0[q * 8 + 0], hA.x, a);
                a = fdot2a(rwhh0[q * 8 + 1], hA.y, a);
                a = fdot2a(rwhh0[q * 8 + 2], hA.z, a);
                a = fdot2a(rwhh0[q * 8 + 3], hA.w, a);
                a = fdot2a(rwhh0[q * 8 + 4], hB.x, a);
                a = fdot2a(rwhh0[q * 8 + 5], hB.y, a);
                a = fdot2a(rwhh0[q * 8 + 6], hB.z, a);
                a = fdot2a(rwhh0[q * 8 + 7], hB.w, a);
                *aq = a;
            }
        }
        float w = red8(a0, a1, a2, a3, l) + bias0;
        float act = 1.0f - A2 / (__expf(A2 * w) + 1.0f);
        {
            float gi = __shfl(act, bl + 0);
            float gg = __shfl(act, bl + 1);
            float gf = __shfl(act, bl + 2);
            float go = __shfl(act, bl + 3);
            c0 = gf * c0 + gi * gg;
            float hh = go * tanh_f(c0);
            if (l == 0) ((_Float16*)h0b[1 - p])[j] = (_Float16)hh;
        }
        __syncthreads();

        // ================= layer 1 =================
        {
            uint4 hA = *(const uint4*)&h0b[1 - p][l * 8];
            uint4 hB = *(const uint4*)&h0b[1 - p][l * 8 + 4];
            uint4 rA = *(const uint4*)&h1b[p][l * 8];
            uint4 rB = *(const uint4*)&h1b[p][l * 8 + 4];
            a0 = 0.0f; a1 = 0.0f; a2 = 0.0f; a3 = 0.0f;
            #pragma unroll
            for (int q = 0; q < 4; ++q) {
                float* aq = (q == 0) ? &a0 : (q == 1) ? &a1 : (q == 2) ? &a2 : &a3;
                float a = *aq;
                a = fdot2a(rwih1[q * 8 + 0], hA.x, a);
                a = fdot2a(rwih1[q * 8 + 1], hA.y, a);
                a = fdot2a(rwih1[q * 8 + 2], hA.z, a);
                a = fdot2a(rwih1[q * 8 + 3], hA.w, a);
                a = fdot2a(rwih1[q * 8 + 4], hB.x, a);
                a = fdot2a(rwih1[q * 8 + 5], hB.y, a);
                a = fdot2a(rwih1[q * 8 + 6], hB.z, a);
                a = fdot2a(rwih1[q * 8 + 7], hB.w, a);
                a = fdot2a(rwhh1[q * 8 + 0], rA.x, a);
                a = fdot2a(rwhh1[q * 8 + 1], rA.y, a);
                a = fdot2a(rwhh1[q * 8 + 2], rA.z, a);
                a = fdot2a(rwhh1[q * 8 + 3], rA.w, a);
                a = fdot2a(rwhh1[q * 8 + 4], rB.x, a);
                a = fdot2a(rwhh1[q * 8 + 5], rB.y, a);
                a = fdot2a(rwhh1[q * 8 + 6], rB.z, a);
                a = fdot2a(rwhh1[q * 8 + 7], rB.w, a);
                *aq = a;
            }
        }
        w = red8(a0, a1, a2, a3, l) + bias1;
        act = 1.0f - A2 / (__expf(A2 * w) + 1.0f);
        {
            float gi = __shfl(act, bl + 0);
            float gg = __shfl(act, bl + 1);
            float gf = __shfl(act, bl + 2);
            float go = __shfl(act, bl + 3);
            c1 = gf * c1 + gi * gg;
            float hh = go * tanh_f(c1);
            if (l == 0) ((_Float16*)h1b[1 - p])[j] = (_Float16)hh;
        }
        __syncthreads();

        // ---------- output linear: wave 0, overlaps next step ----------
        if (tid < 64) {
            int fo = tid >> 3;
            int ll = tid & 7;
            float a = 0.0f;
            #pragma unroll
            for (int jj = 0; jj < 8; ++jj) {
                a = fdot2a(wlin_p[fo * 64 + ll * 8 + jj], h1b[1 - p][ll * 8 + jj], a);
            }
            a += __shfl_down(a, 4, 8);
            a += __shfl_down(a, 2, 8);
            a += __shfl_down(a, 1, 8);
            if (ll == 0) {
                out[((size_t)b * T_ + t) * F_ + fo] = a + blin_f[fo];
            }
        }
        p ^= 1;
    }
}

extern "C" void kernel_launch(void* const* d_in, const int* in_sizes, int n_in,
                              void* d_out, int out_size, void* d_ws, size_t ws_size,
                              hipStream_t stream) {
    const float* x    = (const float*)d_in[0];
    const float* wih0 = (const float*)d_in[1];
    const float* whh0 = (const float*)d_in[2];
    const float* bih0 = (const float*)d_in[3];
    const float* bhh0 = (const float*)d_in[4];
    const float* wih1 = (const float*)d_in[5];
    const float* whh1 = (const float*)d_in[6];
    const float* bih1 = (const float*)d_in[7];
    const float* bhh1 = (const float*)d_in[8];
    const float* wlin = (const float*)d_in[9];
    const float* blin = (const float*)d_in[10];
    float* out = (float*)d_out;

    lstm2_fused_kernel<<<dim3(B_), dim3(1024), 0, stream>>>(
        x, wih0, whh0, bih0, bhh0, wih1, whh1, bih1, bhh1, wlin, blin, out);
}

// Round 5
// 5436.890 us; speedup vs baseline: 1.0282x; 1.0141x over previous
//
#include <hip/hip_runtime.h>

#define B_ 64
#define T_ 2048
#define F_ 8
#define H_ 128
#define G_ 512   // 4*H

typedef _Float16 v2h __attribute__((ext_vector_type(2)));

// pack two fp32 into one dword of two f16 (RTN)
__device__ __forceinline__ unsigned pk2h(float lo, float hi) {
    v2h p;
    p[0] = (_Float16)lo;
    p[1] = (_Float16)hi;
    return __builtin_bit_cast(unsigned, p);
}

#if __has_builtin(__builtin_amdgcn_fdot2)
__device__ __forceinline__ float fdot2a(unsigned a, unsigned b, float c) {
    return __builtin_amdgcn_fdot2(__builtin_bit_cast(v2h, a),
                                  __builtin_bit_cast(v2h, b), c, false);
}
#else
__device__ __forceinline__ float fdot2a(unsigned a, unsigned b, float c) {
    v2h av = __builtin_bit_cast(v2h, a);
    v2h bv = __builtin_bit_cast(v2h, b);
    c += (float)av[0] * (float)bv[0];
    c += (float)av[1] * (float)bv[1];
    return c;
}
#endif

__device__ __forceinline__ float tanh_f(float x) {
    float e = __expf(2.0f * x);
    return 1.0f - 2.0f / (e + 1.0f);
}

// 8-lane compacting butterfly: input 4 gate-partials (each a K-partial),
// output: lane base+0 -> gate0(i), +1 -> gate2(g), +2 -> gate1(f), +3 -> gate3(o)
// full sums (lanes +4..+7 mirror +0..+3).
__device__ __forceinline__ float red8(float v0, float v1, float v2, float v3, int l) {
    float s0 = v0 + __shfl_xor(v0, 1);
    float s1 = v1 + __shfl_xor(v1, 1);
    float s2 = v2 + __shfl_xor(v2, 1);
    float s3 = v3 + __shfl_xor(v3, 1);
    float u0 = (l & 1) ? s2 : s0;
    float u1 = (l & 1) ? s3 : s1;
    float z0 = u0 + __shfl_xor(u0, 2);
    float z1 = u1 + __shfl_xor(u1, 2);
    float w  = (l & 2) ? z1 : z0;
    w += __shfl_xor(w, 4);
    return w;
}

// LDS sized past 80 KB on purpose: 2 WGs can't co-reside (2x87KB > 160KB), so the
// compiler's achievable occupancy = 1 WG = 4 waves/EU -> VGPR budget 128, which
// fits our ~115 live dwords spill-free. (At 36KB LDS the allocator targeted
// 8 waves/EU -> 64 VGPRs -> ~25MB/launch scratch spill traffic; R3/R4 evidence.)
#define XPAD 4608

__global__ void __launch_bounds__(1024, 4)
lstm2_fused_kernel(const float* __restrict__ x,
                   const float* __restrict__ wih0,
                   const float* __restrict__ whh0,
                   const float* __restrict__ bih0,
                   const float* __restrict__ bhh0,
                   const float* __restrict__ wih1,
                   const float* __restrict__ whh1,
                   const float* __restrict__ bih1,
                   const float* __restrict__ bhh1,
                   const float* __restrict__ wlin,
                   const float* __restrict__ blin,
                   float* __restrict__ out)
{
    __shared__ __align__(16) float x_f[T_ * F_ + XPAD];   // fp32 x, 84 KB (oversized)
    __shared__ __align__(16) unsigned h0b[2][H_ / 2];      // h0 double-buffered, f16 pairs
    __shared__ __align__(16) unsigned h1b[2][H_ / 2];      // h1 double-buffered
    __shared__ __align__(16) unsigned wlin_p[G_];
    __shared__ float blin_f[F_];

    const int tid = threadIdx.x;    // 0..1023
    const int j   = tid >> 3;       // h index 0..127
    const int l   = tid & 7;        // K-slice / lane-in-group
    const int b   = blockIdx.x;
    // gate owned by this lane after red8 compaction: 0->i,1->g,2->f,3->o
    const int l3   = l & 3;
    const int gate = ((l3 & 1) << 1) | (l3 >> 1);   // 0,2,1,3

    // ---- stage x[b] into LDS (fp32, exact) ----
    const float4* xp = (const float4*)(x + (size_t)b * T_ * F_);
    #pragma unroll
    for (int i = 0; i < 4; ++i) {
        int idx = tid + i * 1024;
        float4 v = xp[idx];
        *(float4*)&x_f[idx * 4] = v;
    }

    // ---- weights: rows {q*128+j}, K-slice [16l,16l+16), all 3 H-matrices ----
    unsigned rwhh0[32], rwih1[32], rwhh1[32];   // [q*8 + d]
    float    w0f[4];                            // wih0[q*128+j][l] (f32)
    #pragma unroll
    for (int q = 0; q < 4; ++q) {
        const float4* p0 = (const float4*)(whh0 + (size_t)(q * H_ + j) * H_ + l * 16);
        const float4* p1 = (const float4*)(wih1 + (size_t)(q * H_ + j) * H_ + l * 16);
        const float4* p2 = (const float4*)(whh1 + (size_t)(q * H_ + j) * H_ + l * 16);
        #pragma unroll
        for (int i = 0; i < 4; ++i) {
            float4 v0 = p0[i], v1 = p1[i], v2 = p2[i];
            rwhh0[q * 8 + i * 2 + 0] = pk2h(v0.x, v0.y);
            rwhh0[q * 8 + i * 2 + 1] = pk2h(v0.z, v0.w);
            rwih1[q * 8 + i * 2 + 0] = pk2h(v1.x, v1.y);
            rwih1[q * 8 + i * 2 + 1] = pk2h(v1.z, v1.w);
            rwhh1[q * 8 + i * 2 + 0] = pk2h(v2.x, v2.y);
            rwhh1[q * 8 + i * 2 + 1] = pk2h(v2.z, v2.w);
        }
        w0f[q] = wih0[(size_t)(q * H_ + j) * F_ + l];
    }
    // per-lane bias for the gate this lane ends up owning
    const float bias0 = bih0[gate * H_ + j] + bhh0[gate * H_ + j];
    const float bias1 = bih1[gate * H_ + j] + bhh1[gate * H_ + j];
    const float A2 = (gate == 2) ? 2.0f : 1.0f;   // tanh for g-gate, sigmoid else

    if (tid < G_) wlin_p[tid] = pk2h(wlin[tid * 2], wlin[tid * 2 + 1]);
    if (tid < F_) blin_f[tid] = blin[tid];
    if (tid < H_) { ((unsigned*)h0b)[tid] = 0u; ((unsigned*)h1b)[tid] = 0u; }
    __syncthreads();

    const int bl = (tid & 63) & ~7;   // wave-lane base of this 8-group
    float c0 = 0.0f, c1 = 0.0f;       // replicated across all 8 lanes of group
    int p = 0;

    for (int t = 0; t < T_; ++t) {
        // ================= layer 0 =================
        float a0, a1, a2, a3;
        {   // x contribution: lane l handles feature l (fp32 exact)
            float xv = x_f[t * F_ + l];
            a0 = w0f[0] * xv; a1 = w0f[1] * xv;
            a2 = w0f[2] * xv; a3 = w0f[3] * xv;
        }
        {
            uint4 hA = *(const uint4*)&h0b[p][l * 8];
            uint4 hB = *(const uint4*)&h0b[p][l * 8 + 4];
            #pragma unroll
            for (int q = 0; q < 4; ++q) {
                float* aq = (q == 0) ? &a0 : (q == 1) ? &a1 : (q == 2) ? &a2 : &a3;
                float a = *aq;
                a = fdot2a(rwhh0[q * 8 + 0], hA.x, a);
                a = fdot2a(rwhh0[q * 8 + 1], hA.y, a);
                a = fdot2a(rwhh0[q * 8 + 2], hA.z, a);
                a = fdot2a(rwhh0[q * 8 + 3], hA.w, a);
                a = fdot2a(rwhh0[q * 8 + 4], hB.x, a);
                a = fdot2a(rwhh0[q * 8 + 5], hB.y, a);
                a = fdot2a(rwhh0[q * 8 + 6], hB.z, a);
                a = fdot2a(rwhh0[q * 8 + 7], hB.w, a);
                *aq = a;
            }
        }
        float w = red8(a0, a1, a2, a3, l) + bias0;
        float act = 1.0f - A2 / (__expf(A2 * w) + 1.0f);
        {
            float gi = __shfl(act, bl + 0);
            float gg = __shfl(act, bl + 1);
            float gf = __shfl(act, bl + 2);
            float go = __shfl(act, bl + 3);
            c0 = gf * c0 + gi * gg;
            float hh = go * tanh_f(c0);
            if (l == 0) ((_Float16*)h0b[1 - p])[j] = (_Float16)hh;
        }
        __syncthreads();

        // ================= layer 1 =================
        {
            uint4 hA = *(const uint4*)&h0b[1 - p][l * 8];
            uint4 hB = *(const uint4*)&h0b[1 - p][l * 8 + 4];
            uint4 rA = *(const uint4*)&h1b[p][l * 8];
            uint4 rB = *(const uint4*)&h1b[p][l * 8 + 4];
            a0 = 0.0f; a1 = 0.0f; a2 = 0.0f; a3 = 0.0f;
            #pragma unroll
            for (int q = 0; q < 4; ++q) {
                float* aq = (q == 0) ? &a0 : (q == 1) ? &a1 : (q == 2) ? &a2 : &a3;
                float a = *aq;
                a = fdot2a(rwih1[q * 8 + 0], hA.x, a);
                a = fdot2a(rwih1[q * 8 + 1], hA.y, a);
                a = fdot2a(rwih1[q * 8 + 2], hA.z, a);
                a = fdot2a(rwih1[q * 8 + 3], hA.w, a);
                a = fdot2a(rwih1[q * 8 + 4], hB.x, a);
                a = fdot2a(rwih1[q * 8 + 5], hB.y, a);
                a = fdot2a(rwih1[q * 8 + 6], hB.z, a);
                a = fdot2a(rwih1[q * 8 + 7], hB.w, a);
                a = fdot2a(rwhh1[q * 8 + 0], rA.x, a);
                a = fdot2a(rwhh1[q * 8 + 1], rA.y, a);
                a = fdot2a(rwhh1[q * 8 + 2], rA.z, a);
                a = fdot2a(rwhh1[q * 8 + 3], rA.w, a);
                a = fdot2a(rwhh1[q * 8 + 4], rB.x, a);
                a = fdot2a(rwhh1[q * 8 + 5], rB.y, a);
                a = fdot2a(rwhh1[q * 8 + 6], rB.z, a);
                a = fdot2a(rwhh1[q * 8 + 7], rB.w, a);
                *aq = a;
            }
        }
        w = red8(a0, a1, a2, a3, l) + bias1;
        act = 1.0f - A2 / (__expf(A2 * w) + 1.0f);
        {
            float gi = __shfl(act, bl + 0);
            float gg = __shfl(act, bl + 1);
            float gf = __shfl(act, bl + 2);
            float go = __shfl(act, bl + 3);
            c1 = gf * c1 + gi * gg;
            float hh = go * tanh_f(c1);
            if (l == 0) ((_Float16*)h1b[1 - p])[j] = (_Float16)hh;
        }
        __syncthreads();

        // ---------- output linear: wave 0, overlaps next step ----------
        if (tid < 64) {
            int fo = tid >> 3;
            int ll = tid & 7;
            float a = 0.0f;
            #pragma unroll
            for (int jj = 0; jj < 8; ++jj) {
                a = fdot2a(wlin_p[fo * 64 + ll * 8 + jj], h1b[1 - p][ll * 8 + jj], a);
            }
            a += __shfl_down(a, 4, 8);
            a += __shfl_down(a, 2, 8);
            a += __shfl_down(a, 1, 8);
            if (ll == 0) {
                out[((size_t)b * T_ + t) * F_ + fo] = a + blin_f[fo];
            }
        }
        p ^= 1;
    }
}

extern "C" void kernel_launch(void* const* d_in, const int* in_sizes, int n_in,
                              void* d_out, int out_size, void* d_ws, size_t ws_size,
                              hipStream_t stream) {
    const float* x    = (const float*)d_in[0];
    const float* wih0 = (const float*)d_in[1];
    const float* whh0 = (const float*)d_in[2];
    const float* bih0 = (const float*)d_in[3];
    const float* bhh0 = (const float*)d_in[4];
    const float* wih1 = (const float*)d_in[5];
    const float* whh1 = (const float*)d_in[6];
    const float* bih1 = (const float*)d_in[7];
    const float* bhh1 = (const float*)d_in[8];
    const float* wlin = (const float*)d_in[9];
    const float* blin = (const float*)d_in[10];
    float* out = (float*)d_out;

    lstm2_fused_kernel<<<dim3(B_), dim3(1024), 0, stream>>>(
        x, wih0, whh0, bih0, bhh0, wih1, whh1, bih1, bhh1, wlin, blin, out);
}

// Round 6
// 4427.981 us; speedup vs baseline: 1.2625x; 1.2278x over previous
//
#include <hip/hip_runtime.h>

#define B_ 64
#define T_ 2048
#define F_ 8
#define H_ 128
#define G_ 512   // 4*H

typedef _Float16 v2h __attribute__((ext_vector_type(2)));

// pack two fp32 into one dword of two f16 (RTN)
__device__ __forceinline__ unsigned pk2h(float lo, float hi) {
    v2h p;
    p[0] = (_Float16)lo;
    p[1] = (_Float16)hi;
    return __builtin_bit_cast(unsigned, p);
}

#if __has_builtin(__builtin_amdgcn_fdot2)
__device__ __forceinline__ float fdot2a(unsigned a, unsigned b, float c) {
    return __builtin_amdgcn_fdot2(__builtin_bit_cast(v2h, a),
                                  __builtin_bit_cast(v2h, b), c, false);
}
#else
__device__ __forceinline__ float fdot2a(unsigned a, unsigned b, float c) {
    v2h av = __builtin_bit_cast(v2h, a);
    v2h bv = __builtin_bit_cast(v2h, b);
    c += (float)av[0] * (float)bv[0];
    c += (float)av[1] * (float)bv[1];
    return c;
}
#endif

__device__ __forceinline__ float tanh_f(float x) {
    float e = __expf(2.0f * x);
    return 1.0f - 2.0f / (e + 1.0f);
}

// 8-lane compacting butterfly: input 4 gate-partials (each a K-partial),
// output: lane base+0 -> gate0(i), +1 -> gate2(g), +2 -> gate1(f), +3 -> gate3(o)
// full sums (lanes +4..+7 mirror +0..+3).
__device__ __forceinline__ float red8(float v0, float v1, float v2, float v3, int l) {
    float s0 = v0 + __shfl_xor(v0, 1);
    float s1 = v1 + __shfl_xor(v1, 1);
    float s2 = v2 + __shfl_xor(v2, 1);
    float s3 = v3 + __shfl_xor(v3, 1);
    float u0 = (l & 1) ? s2 : s0;
    float u1 = (l & 1) ? s3 : s1;
    float z0 = u0 + __shfl_xor(u0, 2);
    float z1 = u1 + __shfl_xor(u1, 2);
    float w  = (l & 2) ? z1 : z0;
    w += __shfl_xor(w, 4);
    return w;
}

// x kept fp32 and padded so LDS/WG > 80 KB: only 1 WG/CU can fit, matching the
// __launch_bounds__(512,1) declaration (CUDA semantics: min BLOCKS per CU).
// R2/R3/R5 evidence: the 2nd launch_bounds arg = blocks/CU sets the VGPR budget
// (512,2)->128; (1024,4)->64. (512,1) -> 8 waves/CU = 2 waves/EU -> 256 VGPRs,
// which fits our ~240 live dwords spill-free.
#define XNF (T_ * F_ + 4096)

__global__ void __launch_bounds__(512, 1)
lstm2_fused_kernel(const float* __restrict__ x,
                   const float* __restrict__ wih0,
                   const float* __restrict__ whh0,
                   const float* __restrict__ bih0,
                   const float* __restrict__ bhh0,
                   const float* __restrict__ wih1,
                   const float* __restrict__ whh1,
                   const float* __restrict__ bih1,
                   const float* __restrict__ bhh1,
                   const float* __restrict__ wlin,
                   const float* __restrict__ blin,
                   float* __restrict__ out)
{
    __shared__ __align__(16) float x_f[XNF];           // fp32 x, 80+ KB (oversized)
    __shared__ __align__(16) unsigned h0b[2][H_ / 2];  // h0 double-buffered, f16 pairs
    __shared__ __align__(16) unsigned h1b[2][H_ / 2];  // h1 double-buffered
    __shared__ __align__(16) unsigned wlin_p[G_];
    __shared__ float blin_f[F_];

    const int tid = threadIdx.x;    // 0..511
    const int l   = tid & 7;        // K-slice lane within group
    const int grp = tid >> 3;       // 0..63
    const int j0  = grp;            // first h index
    const int j1  = grp + 64;       // second h index
    const int b   = blockIdx.x;
    // gate owned by this lane after red8 compaction: 0->i,1->g,2->f,3->o
    const int l3   = l & 3;
    const int gate = ((l3 & 1) << 1) | (l3 >> 1);   // 0,2,1,3

    // ---- stage x[b] into LDS (fp32, exact) ----
    const float4* xp = (const float4*)(x + (size_t)b * T_ * F_);
    #pragma unroll
    for (int i = 0; i < 8; ++i) {
        int idx = tid + i * 512;
        float4 v = xp[idx];
        *(float4*)&x_f[idx * 4] = v;
    }

    // ---- weights: rows {q*128+j0, q*128+j1}, K-slice [16l,16l+16), 3 matrices ----
    unsigned rwhh0[64], rwih1[64], rwhh1[64];   // [jj*32 + q*8 + d]
    float    w0f[8];                            // wih0[q*128+j][l], [jj*4+q]
    #pragma unroll
    for (int jj = 0; jj < 2; ++jj) {
        int j = jj ? j1 : j0;
        #pragma unroll
        for (int q = 0; q < 4; ++q) {
            const float4* p0 = (const float4*)(whh0 + (size_t)(q * H_ + j) * H_ + l * 16);
            const float4* p1 = (const float4*)(wih1 + (size_t)(q * H_ + j) * H_ + l * 16);
            const float4* p2 = (const float4*)(whh1 + (size_t)(q * H_ + j) * H_ + l * 16);
            #pragma unroll
            for (int i = 0; i < 4; ++i) {
                float4 v0 = p0[i], v1 = p1[i], v2 = p2[i];
                int base = jj * 32 + q * 8 + i * 2;
                rwhh0[base + 0] = pk2h(v0.x, v0.y);
                rwhh0[base + 1] = pk2h(v0.z, v0.w);
                rwih1[base + 0] = pk2h(v1.x, v1.y);
                rwih1[base + 1] = pk2h(v1.z, v1.w);
                rwhh1[base + 0] = pk2h(v2.x, v2.y);
                rwhh1[base + 1] = pk2h(v2.z, v2.w);
            }
            w0f[jj * 4 + q] = wih0[(size_t)(q * H_ + j) * F_ + l];
        }
    }
    // per-lane biases for the gate this lane ends up owning (per j)
    const float bias0_0 = bih0[gate * H_ + j0] + bhh0[gate * H_ + j0];
    const float bias0_1 = bih0[gate * H_ + j1] + bhh0[gate * H_ + j1];
    const float bias1_0 = bih1[gate * H_ + j0] + bhh1[gate * H_ + j0];
    const float bias1_1 = bih1[gate * H_ + j1] + bhh1[gate * H_ + j1];
    const float A2 = (gate == 2) ? 2.0f : 1.0f;   // tanh for g-gate, sigmoid else

    wlin_p[tid] = pk2h(wlin[tid * 2], wlin[tid * 2 + 1]);
    if (tid < F_) blin_f[tid] = blin[tid];
    if (tid < H_) { ((unsigned*)h0b)[tid] = 0u; ((unsigned*)h1b)[tid] = 0u; }
    __syncthreads();

    const int bl = (tid & 63) & ~7;   // wave-lane base of this 8-group
    float c00 = 0.0f, c01 = 0.0f;     // layer-0 cells for j0, j1 (replicated in group)
    float c10 = 0.0f, c11 = 0.0f;     // layer-1 cells
    int p = 0;

    for (int t = 0; t < T_; ++t) {
        // ================= layer 0 =================
        float acc[8];
        {   // x contribution: lane l handles feature l (fp32 exact)
            float xv = x_f[t * F_ + l];
            #pragma unroll
            for (int r = 0; r < 8; ++r) acc[r] = w0f[r] * xv;
        }
        {
            uint4 hA = *(const uint4*)&h0b[p][l * 8];
            uint4 hB = *(const uint4*)&h0b[p][l * 8 + 4];
            #pragma unroll
            for (int r = 0; r < 8; ++r) {
                int base = r * 8;   // r = jj*4 + q
                float a = acc[r];
                a = fdot2a(rwhh0[base + 0], hA.x, a);
                a = fdot2a(rwhh0[base + 1], hA.y, a);
                a = fdot2a(rwhh0[base + 2], hA.z, a);
                a = fdot2a(rwhh0[base + 3], hA.w, a);
                a = fdot2a(rwhh0[base + 4], hB.x, a);
                a = fdot2a(rwhh0[base + 5], hB.y, a);
                a = fdot2a(rwhh0[base + 6], hB.z, a);
                a = fdot2a(rwhh0[base + 7], hB.w, a);
                acc[r] = a;
            }
        }
        float w0 = red8(acc[0], acc[1], acc[2], acc[3], l) + bias0_0;
        float w1 = red8(acc[4], acc[5], acc[6], acc[7], l) + bias0_1;
        float act0 = 1.0f - A2 / (__expf(A2 * w0) + 1.0f);
        float act1 = 1.0f - A2 / (__expf(A2 * w1) + 1.0f);
        {
            float gi0 = __shfl(act0, bl + 0), gg0 = __shfl(act0, bl + 1);
            float gf0 = __shfl(act0, bl + 2), go0 = __shfl(act0, bl + 3);
            float gi1 = __shfl(act1, bl + 0), gg1 = __shfl(act1, bl + 1);
            float gf1 = __shfl(act1, bl + 2), go1 = __shfl(act1, bl + 3);
            c00 = gf0 * c00 + gi0 * gg0;
            c01 = gf1 * c01 + gi1 * gg1;
            float hh0 = go0 * tanh_f(c00);
            float hh1 = go1 * tanh_f(c01);
            if (l == 0) {
                _Float16* hp = (_Float16*)h0b[1 - p];
                hp[j0] = (_Float16)hh0;
                hp[j1] = (_Float16)hh1;
            }
        }
        __syncthreads();

        // ================= layer 1 =================
        {
            uint4 hA = *(const uint4*)&h0b[1 - p][l * 8];
            uint4 hB = *(const uint4*)&h0b[1 - p][l * 8 + 4];
            #pragma unroll
            for (int r = 0; r < 8; ++r) {
                int base = r * 8;
                float a = 0.0f;
                a = fdot2a(rwih1[base + 0], hA.x, a);
                a = fdot2a(rwih1[base + 1], hA.y, a);
                a = fdot2a(rwih1[base + 2], hA.z, a);
                a = fdot2a(rwih1[base + 3], hA.w, a);
                a = fdot2a(rwih1[base + 4], hB.x, a);
                a = fdot2a(rwih1[base + 5], hB.y, a);
                a = fdot2a(rwih1[base + 6], hB.z, a);
                a = fdot2a(rwih1[base + 7], hB.w, a);
                acc[r] = a;
            }
            // reuse hA/hB for the recurrent operand to cap live registers
            hA = *(const uint4*)&h1b[p][l * 8];
            hB = *(const uint4*)&h1b[p][l * 8 + 4];
            #pragma unroll
            for (int r = 0; r < 8; ++r) {
                int base = r * 8;
                float a = acc[r];
                a = fdot2a(rwhh1[base + 0], hA.x, a);
                a = fdot2a(rwhh1[base + 1], hA.y, a);
                a = fdot2a(rwhh1[base + 2], hA.z, a);
                a = fdot2a(rwhh1[base + 3], hA.w, a);
                a = fdot2a(rwhh1[base + 4], hB.x, a);
                a = fdot2a(rwhh1[base + 5], hB.y, a);
                a = fdot2a(rwhh1[base + 6], hB.z, a);
                a = fdot2a(rwhh1[base + 7], hB.w, a);
                acc[r] = a;
            }
        }
        w0 = red8(acc[0], acc[1], acc[2], acc[3], l) + bias1_0;
        w1 = red8(acc[4], acc[5], acc[6], acc[7], l) + bias1_1;
        act0 = 1.0f - A2 / (__expf(A2 * w0) + 1.0f);
        act1 = 1.0f - A2 / (__expf(A2 * w1) + 1.0f);
        {
            float gi0 = __shfl(act0, bl + 0), gg0 = __shfl(act0, bl + 1);
            float gf0 = __shfl(act0, bl + 2), go0 = __shfl(act0, bl + 3);
            float gi1 = __shfl(act1, bl + 0), gg1 = __shfl(act1, bl + 1);
            float gf1 = __shfl(act1, bl + 2), go1 = __shfl(act1, bl + 3);
            c10 = gf0 * c10 + gi0 * gg0;
            c11 = gf1 * c11 + gi1 * gg1;
            float hh0 = go0 * tanh_f(c10);
            float hh1 = go1 * tanh_f(c11);
            if (l == 0) {
                _Float16* hp = (_Float16*)h1b[1 - p];
                hp[j0] = (_Float16)hh0;
                hp[j1] = (_Float16)hh1;
            }
        }
        __syncthreads();

        // ---------- output linear: wave 0, overlaps next step ----------
        if (tid < 64) {
            int fo = tid >> 3;
            int ll = tid & 7;
            float a = 0.0f;
            #pragma unroll
            for (int jj = 0; jj < 8; ++jj) {
                a = fdot2a(wlin_p[fo * 64 + ll * 8 + jj], h1b[1 - p][ll * 8 + jj], a);
            }
            a += __shfl_down(a, 4, 8);
            a += __shfl_down(a, 2, 8);
            a += __shfl_down(a, 1, 8);
            if (ll == 0) {
                out[((size_t)b * T_ + t) * F_ + fo] = a + blin_f[fo];
            }
        }
        p ^= 1;
    }
}

extern "C" void kernel_launch(void* const* d_in, const int* in_sizes, int n_in,
                              void* d_out, int out_size, void* d_ws, size_t ws_size,
                              hipStream_t stream) {
    const float* x    = (const float*)d_in[0];
    const float* wih0 = (const float*)d_in[1];
    const float* whh0 = (const float*)d_in[2];
    const float* bih0 = (const float*)d_in[3];
    const float* bhh0 = (const float*)d_in[4];
    const float* wih1 = (const float*)d_in[5];
    const float* whh1 = (const float*)d_in[6];
    const float* bih1 = (const float*)d_in[7];
    const float* bhh1 = (const float*)d_in[8];
    const float* wlin = (const float*)d_in[9];
    const float* blin = (const float*)d_in[10];
    float* out = (float*)d_out;

    lstm2_fused_kernel<<<dim3(B_), dim3(512), 0, stream>>>(
        x, wih0, whh0, bih0, bhh0, wih1, whh1, bih1, bhh1, wlin, blin, out);
}